// Round 20
// baseline (191.334 us; speedup 1.0000x reference)
//
#include <hip/hip_runtime.h>

#define NN 100000
#define NE 1200000
#define NG 512
#define NSEG (3 * NN)
#define BCAP 32                   // per-(rel,dst) bucket capacity (lambda=4, P(deg>=32)~4e-13)

typedef __bf16 bf16x8 __attribute__((ext_vector_type(8)));
typedef float f32x4 __attribute__((ext_vector_type(4)));

// ---- workspace layout (bytes), all 16B-aligned ----
static constexpr size_t AGG_OFF   = 0;                                  // NSEG*64 bf16 (layer-2 agg)
static constexpr size_t AGG_BYTES = (size_t)NSEG * 64 * 2;              // 38.4MB
static constexpr size_t HIST_OFF  = AGG_OFF + AGG_BYTES;                // NSEG ints
static constexpr size_t ESRC_OFF  = HIST_OFF + (size_t)NSEG * 4;        // NSEG*BCAP ints (38.4MB)
static constexpr size_t H1_OFF    = ESRC_OFF + (size_t)NSEG * BCAP * 4; // NN*64 bf16
static constexpr size_t H2_OFF    = H1_OFF + (size_t)NN * 64 * 2;       // NN*64 f32
static constexpr size_t WT2H_OFF  = H2_OFF + (size_t)NN * 64 * 4;       // 64*256 bf16
static constexpr size_t WT2L_OFF  = WT2H_OFF + 64 * 256 * 2;
static constexpr size_t TW_OFF    = WT2L_OFF + 64 * 256 * 2;            // 4*256*64 f32 (tRoot,tW1[0..2])
static constexpr size_t CB_OFF    = TW_OFF + 4 * 256 * 64 * 4;          // NN bytes

// async global->LDS, 16B per lane
__device__ __forceinline__ void async_copy16(void* lds, const void* g) {
    __builtin_amdgcn_global_load_lds(
        (const __attribute__((address_space(1))) void*)g,
        (__attribute__((address_space(3))) void*)lds, 16, 0, 0);
}

__device__ __forceinline__ void prepw_elem(const float* root, const float* w,
                                           __bf16* wh, __bf16* wl, int cin, int t) {
    int kt = 4 * cin;
    if (t >= 64 * kt) return;
    int j = t / kt, k = t % kt;
    int sidx = k / cin, kk = k % cin;
    float v = (sidx == 0) ? root[kk * 64 + j]
                          : w[((size_t)(sidx - 1) * cin + kk) * 64 + j];
    __bf16 h = (__bf16)v;
    wh[t] = h;
    wl[t] = (__bf16)(v - (float)h);
}

// compute one combo row (32 outputs) of the pre-MLP from LDS sW/sB
__device__ __forceinline__ void combo_row(int cmb, const float* se, const float* ce,
                                          const float* sW, const float* sB, float* outr) {
    int s = cmb >> 4, c = cmb & 15;
    float in[16];
#pragma unroll
    for (int k = 0; k < 8; k++) in[k] = se[s * 8 + k];
#pragma unroll
    for (int k = 0; k < 8; k++) in[8 + k] = ce[c * 8 + k];
    float acc[32];
#pragma unroll
    for (int j = 0; j < 32; j++) acc[j] = sB[j];
#pragma unroll
    for (int k = 0; k < 16; k++) {
        float hv = in[k];
#pragma unroll
        for (int j = 0; j < 32; j++) acc[j] += hv * sW[k * 32 + j];
    }
#pragma unroll
    for (int j = 0; j < 32; j++) outr[j] = fmaxf(acc[j], 0.f);
}

// ---- table build (LDS-heavy, isolated so the rank kernel stays LDS-free):
// 16 blocks: tRoot = b1 + table@root1 (blocks 0..3); tW1r = table@W1_r (4..15)
__global__ __launch_bounds__(256)
void k_tw(const float* __restrict__ se, const float* __restrict__ ce,
          const float* __restrict__ pw, const float* __restrict__ pb,
          const float* __restrict__ root1, const float* __restrict__ w1,
          const float* __restrict__ b1, float* __restrict__ tw) {
    int b = blockIdx.x, t = threadIdx.x;
    __shared__ float sW[16 * 32];
    __shared__ float sB[32];
    __shared__ float sTab[256 * 33];
    for (int i = t; i < 512; i += 256) sW[i] = pw[i];
    if (t < 32) sB[t] = pb[t];
    __syncthreads();
    {
        float row[32];
        combo_row(t, se, ce, sW, sB, row);
#pragma unroll
        for (int j = 0; j < 32; j++) sTab[t * 33 + j] = row[j];
    }
    __syncthreads();
    int ti = b >> 2;                      // 0..3: tRoot, tW1[0..2]
    int row = (b & 3) * 64 + (t >> 2);
    int c0 = (t & 3) * 16;
    const float* Wsrc = (ti == 0) ? root1 : (w1 + (size_t)(ti - 1) * 32 * 64);
    float acc[16];
#pragma unroll
    for (int j = 0; j < 16; j++) acc[j] = (ti == 0) ? b1[c0 + j] : 0.f;
    for (int k = 0; k < 32; k++) {
        float hv = sTab[row * 33 + k];
#pragma unroll
        for (int j = 0; j < 16; j++) acc[j] += hv * Wsrc[k * 64 + c0 + j];
    }
    float* o = tw + (size_t)ti * 256 * 64 + (size_t)row * 64 + c0;
#pragma unroll
    for (int j = 0; j < 16; j += 4)
        *(float4*)(o + j) = make_float4(acc[j], acc[j + 1], acc[j + 2], acc[j + 3]);
}

// ---- fused (all LDS-free): prep W2-split (0..63) + cb bytes (64..454) + rank (455..)
#define RB_BASE 455
__global__ __launch_bounds__(256)
void k_rank_prep(const int* __restrict__ ei, const int* __restrict__ et,
                 int* __restrict__ hist, int* __restrict__ esrc,
                 const int* __restrict__ x,
                 const float* __restrict__ root2, const float* __restrict__ w2,
                 __bf16* __restrict__ wh2, __bf16* __restrict__ wl2,
                 unsigned char* __restrict__ cb) {
    int b = blockIdx.x, t = threadIdx.x;
    if (b >= RB_BASE) {
        int e = (b - RB_BASE) * 256 + t;
        if (e >= NE) return;
        int s = ei[e];
        int d = ei[NE + e];
        int r = et[e];
        int x0 = x[2 * s], x1 = x[2 * s + 1];      // independent loads, fill shadow
        int seg = r * NN + d;
        int rank = atomicAdd(&hist[seg], 1);
        if (rank < BCAP)
            esrc[(size_t)seg * BCAP + rank] = s | ((x0 * 16 + x1) << 17);
        return;
    }
    if (b < 64) {
        prepw_elem(root2, w2, wh2, wl2, 64, b * 256 + t);
    } else {
        int n = (b - 64) * 256 + t;
        if (n < NN) cb[n] = (unsigned char)(x[2 * n] * 16 + x[2 * n + 1]);
    }
}

// ---- layer 1 (fused): h1[n] = relu(tRoot[cb[n]] + sum_r mean_r(tW1r[cmb(src)]))
__global__ __launch_bounds__(256)
void k_l1(const int* __restrict__ hist, const int* __restrict__ esrc,
          const unsigned char* __restrict__ cb,
          const float* __restrict__ tw, __bf16* __restrict__ h1b) {
    int tid = blockIdx.x * 256 + threadIdx.x;
    int n = tid >> 3;
    int p = tid & 7;
    if (n >= NN) return;
    const float* tr = tw + (size_t)cb[n] * 64 + p * 8;
    float4 a0 = *(const float4*)tr;
    float4 a1 = *(const float4*)(tr + 4);
#pragma unroll
    for (int r = 0; r < 3; r++) {
        const float* tb = tw + (size_t)(r + 1) * 256 * 64 + p * 8;
        int seg = r * NN + n;
        int cnt = hist[seg];
        int m = cnt < BCAP ? cnt : BCAP;
        const int* eb = esrc + (size_t)seg * BCAP;
        float4 r0 = make_float4(0.f, 0.f, 0.f, 0.f);
        float4 r1 = make_float4(0.f, 0.f, 0.f, 0.f);
        for (int i = 0; i < m; i++) {
            int cmb = (eb[i] >> 17) & 0xFF;
            const float* row = tb + (size_t)cmb * 64;
            float4 v0 = *(const float4*)row;
            float4 v1 = *(const float4*)(row + 4);
            r0.x += v0.x; r0.y += v0.y; r0.z += v0.z; r0.w += v0.w;
            r1.x += v1.x; r1.y += v1.y; r1.z += v1.z; r1.w += v1.w;
        }
        float inv = 1.f / (float)(cnt > 1 ? cnt : 1);
        a0.x += r0.x * inv; a0.y += r0.y * inv; a0.z += r0.z * inv; a0.w += r0.w * inv;
        a1.x += r1.x * inv; a1.y += r1.y * inv; a1.z += r1.z * inv; a1.w += r1.w * inv;
    }
    bf16x8 o;
    o[0] = (__bf16)fmaxf(a0.x, 0.f); o[1] = (__bf16)fmaxf(a0.y, 0.f);
    o[2] = (__bf16)fmaxf(a0.z, 0.f); o[3] = (__bf16)fmaxf(a0.w, 0.f);
    o[4] = (__bf16)fmaxf(a1.x, 0.f); o[5] = (__bf16)fmaxf(a1.y, 0.f);
    o[6] = (__bf16)fmaxf(a1.z, 0.f); o[7] = (__bf16)fmaxf(a1.w, 0.f);
    *(bf16x8*)(h1b + (size_t)n * 64 + p * 8) = o;
}

// ---- layer-2 gather: bf16 rows (128B/edge) from buckets; bf16 agg
__global__ __launch_bounds__(256)
void k_gather64(const int* __restrict__ hist, const int* __restrict__ esrc,
                const __bf16* __restrict__ h, __bf16* __restrict__ agg) {
    int tid = blockIdx.x * 256 + threadIdx.x;
    int seg = tid >> 3;
    int p = tid & 7;
    if (seg >= NSEG) return;
    int cnt = hist[seg];
    int m = cnt < BCAP ? cnt : BCAP;
    const int* eb = esrc + (size_t)seg * BCAP;
    float acc[8];
#pragma unroll
    for (int j = 0; j < 8; j++) acc[j] = 0.f;
    int i = 0;
    for (; i + 4 <= m; i += 4) {
        int s0 = eb[i] & 0x1FFFF, s1 = eb[i + 1] & 0x1FFFF;
        int s2 = eb[i + 2] & 0x1FFFF, s3 = eb[i + 3] & 0x1FFFF;
        bf16x8 v0 = *(const bf16x8*)(h + (size_t)s0 * 64 + p * 8);
        bf16x8 v1 = *(const bf16x8*)(h + (size_t)s1 * 64 + p * 8);
        bf16x8 v2 = *(const bf16x8*)(h + (size_t)s2 * 64 + p * 8);
        bf16x8 v3 = *(const bf16x8*)(h + (size_t)s3 * 64 + p * 8);
#pragma unroll
        for (int j = 0; j < 8; j++)
            acc[j] += ((float)v0[j] + (float)v1[j]) + ((float)v2[j] + (float)v3[j]);
    }
    for (; i < m; i++) {
        int s = eb[i] & 0x1FFFF;
        bf16x8 v = *(const bf16x8*)(h + (size_t)s * 64 + p * 8);
#pragma unroll
        for (int j = 0; j < 8; j++) acc[j] += (float)v[j];
    }
    float inv = 1.f / (float)(cnt > 1 ? cnt : 1);
    bf16x8 o;
#pragma unroll
    for (int j = 0; j < 8; j++) o[j] = (__bf16)(acc[j] * inv);
    *(bf16x8*)(agg + (size_t)seg * 64 + p * 8) = o;
}

// ---- layer-2 combine (bf16 A, split-bf16 weights; fp32 out)
__global__ __launch_bounds__(256, 1)
void k_combine_l2(const __bf16* __restrict__ h1b, const __bf16* __restrict__ aggb,
                  const __bf16* __restrict__ wh, const __bf16* __restrict__ wl,
                  const float* __restrict__ bias, float* __restrict__ h_out) {
    constexpr int KT = 256;
    __shared__ __bf16 sINb[64 * 64];
    __shared__ __bf16 sWH[64 * 64];
    __shared__ __bf16 sWL[64 * 64];

    const int tid = threadIdx.x;
    const int wave = tid >> 6;
    const int lane = tid & 63;
    const int cA = lane & 15;
    const int kg = lane >> 4;
    const int n0 = blockIdx.x * 64;

    f32x4 acc[4];
#pragma unroll
    for (int nb = 0; nb < 4; nb++) {
        float bv = bias[nb * 16 + cA];
        acc[nb][0] = bv; acc[nb][1] = bv; acc[nb][2] = bv; acc[nb][3] = bv;
    }

    for (int c = 0; c < 4; c++) {
        if (c) __syncthreads();
#pragma unroll
        for (int i = 0; i < 2; i++) {
            int F = tid + i * 256;
            int row = F >> 3, j = F & 7;
            int jor = j ^ (row & 7);
            int n = n0 + row; if (n > NN - 1) n = NN - 1;
            const __bf16* src = (c == 0)
                ? h1b + (size_t)n * 64 + jor * 8
                : aggb + ((size_t)(c - 1) * NN + n) * 64 + jor * 8;
            async_copy16(sINb + (size_t)F * 8, src);
        }
#pragma unroll
        for (int i = 0; i < 2; i++) {
            int F = tid + i * 256;
            int col = F >> 3, s = F & 7;
            int sor = s ^ (col & 7);
            async_copy16(sWH + (size_t)F * 8, wh + (size_t)col * KT + c * 64 + sor * 8);
            async_copy16(sWL + (size_t)F * 8, wl + (size_t)col * KT + c * 64 + sor * 8);
        }
        __syncthreads();
#pragma unroll
        for (int ks = 0; ks < 2; ks++) {
            const int rowL = wave * 16 + cA;
            const int s8 = ks * 4 + kg;
            bf16x8 ah = ((const bf16x8*)sINb)[rowL * 8 + (s8 ^ (rowL & 7))];
#pragma unroll
            for (int nb = 0; nb < 4; nb++) {
                const int col = nb * 16 + cA;
                const int bs = col * 8 + (s8 ^ (col & 7));
                bf16x8 bh = ((const bf16x8*)sWH)[bs];
                bf16x8 bl = ((const bf16x8*)sWL)[bs];
                acc[nb] = __builtin_amdgcn_mfma_f32_16x16x32_bf16(ah, bh, acc[nb], 0, 0, 0);
                acc[nb] = __builtin_amdgcn_mfma_f32_16x16x32_bf16(ah, bl, acc[nb], 0, 0, 0);
            }
        }
    }
#pragma unroll
    for (int nb = 0; nb < 4; nb++) {
#pragma unroll
        for (int r = 0; r < 4; r++) {
            int n = n0 + wave * 16 + kg * 4 + r;
            if (n < NN)
                h_out[(size_t)n * 64 + nb * 16 + cA] = fmaxf(acc[nb][r], 0.f);
        }
    }
}

// ---- fused mean-pool + classifier: block g -> out[g][0..9]
__global__ __launch_bounds__(256)
void k_pool_final(const float* __restrict__ h, const int* __restrict__ batch,
                  const float* __restrict__ cw, const float* __restrict__ cbias,
                  float* __restrict__ out) {
    int g = blockIdx.x;
    auto lb = [&](int v) {
        int lo = 0, hi = NN;
        while (lo < hi) {
            int m = (lo + hi) >> 1;
            if (batch[m] < v) lo = m + 1; else hi = m;
        }
        return lo;
    };
    int st = lb(g), en = lb(g + 1);
    int col = threadIdx.x & 63, chunk = threadIdx.x >> 6;
    float acc = 0.f;
    for (int n = st + chunk; n < en; n += 4) acc += h[(size_t)n * 64 + col];
    __shared__ float s[256];
    __shared__ float mean[64];
    s[threadIdx.x] = acc;
    __syncthreads();
    if (chunk == 0) {
        float tot = s[col] + s[64 + col] + s[128 + col] + s[192 + col];
        int c = en - st;
        mean[col] = tot / (float)(c > 1 ? c : 1);
    }
    __syncthreads();
    if (threadIdx.x < 10) {
        int j = threadIdx.x;
        float o = cbias[j];
#pragma unroll
        for (int k = 0; k < 64; k++) o += mean[k] * cw[k * 10 + j];
        out[g * 10 + j] = o;
    }
}

extern "C" void kernel_launch(void* const* d_in, const int* in_sizes, int n_in,
                              void* d_out, int out_size, void* d_ws, size_t ws_size,
                              hipStream_t stream) {
    const int* x      = (const int*)d_in[0];
    const int* ei     = (const int*)d_in[1];
    const int* et     = (const int*)d_in[2];
    const int* batch  = (const int*)d_in[3];
    const float* se   = (const float*)d_in[4];
    const float* ce   = (const float*)d_in[5];
    const float* pw   = (const float*)d_in[6];
    const float* pb   = (const float*)d_in[7];
    const float* w1   = (const float*)d_in[8];
    const float* root1= (const float*)d_in[9];
    const float* b1   = (const float*)d_in[10];
    const float* w2   = (const float*)d_in[11];
    const float* root2= (const float*)d_in[12];
    const float* b2   = (const float*)d_in[13];
    const float* cw   = (const float*)d_in[14];
    const float* cbias= (const float*)d_in[15];
    float* out = (float*)d_out;

    char* ws = (char*)d_ws;
    __bf16* aggb = (__bf16*)(ws + AGG_OFF);
    int*   hist  = (int*)(ws + HIST_OFF);
    int*   esrc  = (int*)(ws + ESRC_OFF);
    __bf16* h1b  = (__bf16*)(ws + H1_OFF);
    float* h2    = (float*)(ws + H2_OFF);
    __bf16* wt2h = (__bf16*)(ws + WT2H_OFF);
    __bf16* wt2l = (__bf16*)(ws + WT2L_OFF);
    float* tw    = (float*)(ws + TW_OFF);
    unsigned char* cbarr = (unsigned char*)(ws + CB_OFF);

    // zero the histogram only (1.2MB)
    (void)hipMemsetAsync(hist, 0, (size_t)NSEG * 4, stream);

    // table build (LDS-heavy, 16 blocks)
    k_tw<<<16, 256, 0, stream>>>(se, ce, pw, pb, root1, w1, b1, tw);

    // fused LDS-free prep + rank-and-place (full occupancy)
    int rank_blocks = RB_BASE + (NE + 255) / 256;
    k_rank_prep<<<rank_blocks, 256, 0, stream>>>(ei, et, hist, esrc, x,
                                                 root2, w2, wt2h, wt2l, cbarr);

    // layer 1 (fully fused via weighted tables)
    k_l1<<<(NN * 8 + 255) / 256, 256, 0, stream>>>(hist, esrc, cbarr, tw, h1b);

    // layer 2
    k_gather64<<<(NSEG * 8 + 255) / 256, 256, 0, stream>>>(hist, esrc, h1b, aggb);
    k_combine_l2<<<(NN + 63) / 64, 256, 0, stream>>>(h1b, aggb, wt2h, wt2l, b2, h2);

    // fused pooling + classifier
    k_pool_final<<<NG, 256, 0, stream>>>(h2, batch, cw, cbias, out);
}

// Round 21
// 190.016 us; speedup vs baseline: 1.0069x; 1.0069x over previous
//
#include <hip/hip_runtime.h>

#define NN 100000
#define NE 1200000
#define NG 512
#define NSEG (3 * NN)
#define BCAP 32                   // per-(rel,dst) bucket capacity (lambda=4, P(deg>=32)~4e-13)

typedef __bf16 bf16x8 __attribute__((ext_vector_type(8)));
typedef float f32x4 __attribute__((ext_vector_type(4)));

// ---- workspace layout (bytes), all 16B-aligned ----
static constexpr size_t AGG_OFF   = 0;                                  // NSEG*64 bf16 (layer-2 agg)
static constexpr size_t AGG_BYTES = (size_t)NSEG * 64 * 2;              // 38.4MB
static constexpr size_t HIST_OFF  = AGG_OFF + AGG_BYTES;                // NSEG ints
static constexpr size_t ESRC_OFF  = HIST_OFF + (size_t)NSEG * 4;        // NSEG*BCAP ints (38.4MB)
static constexpr size_t H1_OFF    = ESRC_OFF + (size_t)NSEG * BCAP * 4; // NN*64 bf16
static constexpr size_t H2_OFF    = H1_OFF + (size_t)NN * 64 * 2;       // NN*64 f32
static constexpr size_t WT2H_OFF  = H2_OFF + (size_t)NN * 64 * 4;       // 64*256 bf16
static constexpr size_t WT2L_OFF  = WT2H_OFF + 64 * 256 * 2;
static constexpr size_t TW_OFF    = WT2L_OFF + 64 * 256 * 2;            // 4*256*64 f32 (tRoot,tW1[0..2])
static constexpr size_t CB_OFF    = TW_OFF + 4 * 256 * 64 * 4;          // NN bytes

// async global->LDS, 16B per lane
__device__ __forceinline__ void async_copy16(void* lds, const void* g) {
    __builtin_amdgcn_global_load_lds(
        (const __attribute__((address_space(1))) void*)g,
        (__attribute__((address_space(3))) void*)lds, 16, 0, 0);
}

__device__ __forceinline__ void prepw_elem(const float* root, const float* w,
                                           __bf16* wh, __bf16* wl, int cin, int t) {
    int kt = 4 * cin;
    if (t >= 64 * kt) return;
    int j = t / kt, k = t % kt;
    int sidx = k / cin, kk = k % cin;
    float v = (sidx == 0) ? root[kk * 64 + j]
                          : w[((size_t)(sidx - 1) * cin + kk) * 64 + j];
    __bf16 h = (__bf16)v;
    wh[t] = h;
    wl[t] = (__bf16)(v - (float)h);
}

// compute one combo row (32 outputs) of the pre-MLP, all in registers
__device__ __forceinline__ void combo_row_g(int cmb, const float* __restrict__ se,
                                            const float* __restrict__ ce,
                                            const float* __restrict__ pw,
                                            const float* __restrict__ pb, float* outr) {
    int s = cmb >> 4, c = cmb & 15;
    float in[16];
#pragma unroll
    for (int k = 0; k < 8; k++) in[k] = se[s * 8 + k];
#pragma unroll
    for (int k = 0; k < 8; k++) in[8 + k] = ce[c * 8 + k];
    float acc[32];
#pragma unroll
    for (int j = 0; j < 32; j++) acc[j] = pb[j];
#pragma unroll
    for (int k = 0; k < 16; k++) {
        float hv = in[k];
#pragma unroll
        for (int j = 0; j < 32; j++) acc[j] += hv * pw[k * 32 + j];
    }
#pragma unroll
    for (int j = 0; j < 32; j++) outr[j] = fmaxf(acc[j], 0.f);
}

// ---- fused, ALL LDS-free: W2-split (0..63) + tW build (64..79) + cb (80..470) + rank (471..)
// tW build: thread computes its combo row in registers (4x redundant), then a
// 32x16 product from L2-cached weights -> no LDS -> rank blocks keep full occupancy
// and the table build overlaps the atomic pass instead of serializing.
#define RB_BASE 471
__global__ __launch_bounds__(256)
void k_rank_prep(const int* __restrict__ ei, const int* __restrict__ et,
                 int* __restrict__ hist, int* __restrict__ esrc,
                 const int* __restrict__ x, const float* __restrict__ se,
                 const float* __restrict__ ce, const float* __restrict__ pw,
                 const float* __restrict__ pb,
                 const float* __restrict__ root1, const float* __restrict__ w1,
                 const float* __restrict__ b1,
                 const float* __restrict__ root2, const float* __restrict__ w2,
                 __bf16* __restrict__ wh2, __bf16* __restrict__ wl2,
                 float* __restrict__ tw, unsigned char* __restrict__ cb) {
    int b = blockIdx.x, t = threadIdx.x;
    if (b >= RB_BASE) {
        int e = (b - RB_BASE) * 256 + t;
        if (e >= NE) return;
        int s = ei[e];
        int d = ei[NE + e];
        int r = et[e];
        int2 xv = *(const int2*)(x + 2 * s);       // independent 8B load, fills shadow
        int seg = r * NN + d;
        int rank = atomicAdd(&hist[seg], 1);
        if (rank < BCAP)
            esrc[(size_t)seg * BCAP + rank] = s | ((xv.x * 16 + xv.y) << 17);
        return;
    }
    if (b < 64) {
        prepw_elem(root2, w2, wh2, wl2, 64, b * 256 + t);
    } else if (b < 80) {
        int ti = (b - 64) >> 2;               // 0..3: tRoot, tW1[0..2]
        int row = ((b - 64) & 3) * 64 + (t >> 2);
        int c0 = (t & 3) * 16;
        float trow[32];
        combo_row_g(row, se, ce, pw, pb, trow);
        const float* Wsrc = (ti == 0) ? root1 : (w1 + (size_t)(ti - 1) * 32 * 64);
        float acc[16];
#pragma unroll
        for (int j = 0; j < 16; j++) acc[j] = (ti == 0) ? b1[c0 + j] : 0.f;
        for (int k = 0; k < 32; k++) {
            float hv = trow[k];
#pragma unroll
            for (int j = 0; j < 16; j++) acc[j] += hv * Wsrc[k * 64 + c0 + j];
        }
        float* o = tw + (size_t)ti * 256 * 64 + (size_t)row * 64 + c0;
#pragma unroll
        for (int j = 0; j < 16; j += 4)
            *(float4*)(o + j) = make_float4(acc[j], acc[j + 1], acc[j + 2], acc[j + 3]);
    } else {
        int n = (b - 80) * 256 + t;
        if (n < NN) cb[n] = (unsigned char)(x[2 * n] * 16 + x[2 * n + 1]);
    }
}

// ---- layer 1 (fused): h1[n] = relu(tRoot[cb[n]] + sum_r mean_r(tW1r[cmb(src)]))
__global__ __launch_bounds__(256)
void k_l1(const int* __restrict__ hist, const int* __restrict__ esrc,
          const unsigned char* __restrict__ cb,
          const float* __restrict__ tw, __bf16* __restrict__ h1b) {
    int tid = blockIdx.x * 256 + threadIdx.x;
    int n = tid >> 3;
    int p = tid & 7;
    if (n >= NN) return;
    const float* tr = tw + (size_t)cb[n] * 64 + p * 8;
    float4 a0 = *(const float4*)tr;
    float4 a1 = *(const float4*)(tr + 4);
#pragma unroll
    for (int r = 0; r < 3; r++) {
        const float* tb = tw + (size_t)(r + 1) * 256 * 64 + p * 8;
        int seg = r * NN + n;
        int cnt = hist[seg];
        int m = cnt < BCAP ? cnt : BCAP;
        const int* eb = esrc + (size_t)seg * BCAP;
        float4 r0 = make_float4(0.f, 0.f, 0.f, 0.f);
        float4 r1 = make_float4(0.f, 0.f, 0.f, 0.f);
        for (int i = 0; i < m; i++) {
            int cmb = (eb[i] >> 17) & 0xFF;
            const float* row = tb + (size_t)cmb * 64;
            float4 v0 = *(const float4*)row;
            float4 v1 = *(const float4*)(row + 4);
            r0.x += v0.x; r0.y += v0.y; r0.z += v0.z; r0.w += v0.w;
            r1.x += v1.x; r1.y += v1.y; r1.z += v1.z; r1.w += v1.w;
        }
        float inv = 1.f / (float)(cnt > 1 ? cnt : 1);
        a0.x += r0.x * inv; a0.y += r0.y * inv; a0.z += r0.z * inv; a0.w += r0.w * inv;
        a1.x += r1.x * inv; a1.y += r1.y * inv; a1.z += r1.z * inv; a1.w += r1.w * inv;
    }
    bf16x8 o;
    o[0] = (__bf16)fmaxf(a0.x, 0.f); o[1] = (__bf16)fmaxf(a0.y, 0.f);
    o[2] = (__bf16)fmaxf(a0.z, 0.f); o[3] = (__bf16)fmaxf(a0.w, 0.f);
    o[4] = (__bf16)fmaxf(a1.x, 0.f); o[5] = (__bf16)fmaxf(a1.y, 0.f);
    o[6] = (__bf16)fmaxf(a1.z, 0.f); o[7] = (__bf16)fmaxf(a1.w, 0.f);
    *(bf16x8*)(h1b + (size_t)n * 64 + p * 8) = o;
}

// ---- layer-2 gather: bf16 rows (128B/edge) from buckets; bf16 agg
__global__ __launch_bounds__(256)
void k_gather64(const int* __restrict__ hist, const int* __restrict__ esrc,
                const __bf16* __restrict__ h, __bf16* __restrict__ agg) {
    int tid = blockIdx.x * 256 + threadIdx.x;
    int seg = tid >> 3;
    int p = tid & 7;
    if (seg >= NSEG) return;
    int cnt = hist[seg];
    int m = cnt < BCAP ? cnt : BCAP;
    const int* eb = esrc + (size_t)seg * BCAP;
    float acc[8];
#pragma unroll
    for (int j = 0; j < 8; j++) acc[j] = 0.f;
    int i = 0;
    for (; i + 4 <= m; i += 4) {
        int s0 = eb[i] & 0x1FFFF, s1 = eb[i + 1] & 0x1FFFF;
        int s2 = eb[i + 2] & 0x1FFFF, s3 = eb[i + 3] & 0x1FFFF;
        bf16x8 v0 = *(const bf16x8*)(h + (size_t)s0 * 64 + p * 8);
        bf16x8 v1 = *(const bf16x8*)(h + (size_t)s1 * 64 + p * 8);
        bf16x8 v2 = *(const bf16x8*)(h + (size_t)s2 * 64 + p * 8);
        bf16x8 v3 = *(const bf16x8*)(h + (size_t)s3 * 64 + p * 8);
#pragma unroll
        for (int j = 0; j < 8; j++)
            acc[j] += ((float)v0[j] + (float)v1[j]) + ((float)v2[j] + (float)v3[j]);
    }
    for (; i < m; i++) {
        int s = eb[i] & 0x1FFFF;
        bf16x8 v = *(const bf16x8*)(h + (size_t)s * 64 + p * 8);
#pragma unroll
        for (int j = 0; j < 8; j++) acc[j] += (float)v[j];
    }
    float inv = 1.f / (float)(cnt > 1 ? cnt : 1);
    bf16x8 o;
#pragma unroll
    for (int j = 0; j < 8; j++) o[j] = (__bf16)(acc[j] * inv);
    *(bf16x8*)(agg + (size_t)seg * 64 + p * 8) = o;
}

// ---- layer-2 combine (bf16 A, split-bf16 weights; fp32 out)
__global__ __launch_bounds__(256, 1)
void k_combine_l2(const __bf16* __restrict__ h1b, const __bf16* __restrict__ aggb,
                  const __bf16* __restrict__ wh, const __bf16* __restrict__ wl,
                  const float* __restrict__ bias, float* __restrict__ h_out) {
    constexpr int KT = 256;
    __shared__ __bf16 sINb[64 * 64];
    __shared__ __bf16 sWH[64 * 64];
    __shared__ __bf16 sWL[64 * 64];

    const int tid = threadIdx.x;
    const int wave = tid >> 6;
    const int lane = tid & 63;
    const int cA = lane & 15;
    const int kg = lane >> 4;
    const int n0 = blockIdx.x * 64;

    f32x4 acc[4];
#pragma unroll
    for (int nb = 0; nb < 4; nb++) {
        float bv = bias[nb * 16 + cA];
        acc[nb][0] = bv; acc[nb][1] = bv; acc[nb][2] = bv; acc[nb][3] = bv;
    }

    for (int c = 0; c < 4; c++) {
        if (c) __syncthreads();
#pragma unroll
        for (int i = 0; i < 2; i++) {
            int F = tid + i * 256;
            int row = F >> 3, j = F & 7;
            int jor = j ^ (row & 7);
            int n = n0 + row; if (n > NN - 1) n = NN - 1;
            const __bf16* src = (c == 0)
                ? h1b + (size_t)n * 64 + jor * 8
                : aggb + ((size_t)(c - 1) * NN + n) * 64 + jor * 8;
            async_copy16(sINb + (size_t)F * 8, src);
        }
#pragma unroll
        for (int i = 0; i < 2; i++) {
            int F = tid + i * 256;
            int col = F >> 3, s = F & 7;
            int sor = s ^ (col & 7);
            async_copy16(sWH + (size_t)F * 8, wh + (size_t)col * KT + c * 64 + sor * 8);
            async_copy16(sWL + (size_t)F * 8, wl + (size_t)col * KT + c * 64 + sor * 8);
        }
        __syncthreads();
#pragma unroll
        for (int ks = 0; ks < 2; ks++) {
            const int rowL = wave * 16 + cA;
            const int s8 = ks * 4 + kg;
            bf16x8 ah = ((const bf16x8*)sINb)[rowL * 8 + (s8 ^ (rowL & 7))];
#pragma unroll
            for (int nb = 0; nb < 4; nb++) {
                const int col = nb * 16 + cA;
                const int bs = col * 8 + (s8 ^ (col & 7));
                bf16x8 bh = ((const bf16x8*)sWH)[bs];
                bf16x8 bl = ((const bf16x8*)sWL)[bs];
                acc[nb] = __builtin_amdgcn_mfma_f32_16x16x32_bf16(ah, bh, acc[nb], 0, 0, 0);
                acc[nb] = __builtin_amdgcn_mfma_f32_16x16x32_bf16(ah, bl, acc[nb], 0, 0, 0);
            }
        }
    }
#pragma unroll
    for (int nb = 0; nb < 4; nb++) {
#pragma unroll
        for (int r = 0; r < 4; r++) {
            int n = n0 + wave * 16 + kg * 4 + r;
            if (n < NN)
                h_out[(size_t)n * 64 + nb * 16 + cA] = fmaxf(acc[nb][r], 0.f);
        }
    }
}

// ---- fused mean-pool + classifier: block g -> out[g][0..9]
__global__ __launch_bounds__(256)
void k_pool_final(const float* __restrict__ h, const int* __restrict__ batch,
                  const float* __restrict__ cw, const float* __restrict__ cbias,
                  float* __restrict__ out) {
    int g = blockIdx.x;
    auto lb = [&](int v) {
        int lo = 0, hi = NN;
        while (lo < hi) {
            int m = (lo + hi) >> 1;
            if (batch[m] < v) lo = m + 1; else hi = m;
        }
        return lo;
    };
    int st = lb(g), en = lb(g + 1);
    int col = threadIdx.x & 63, chunk = threadIdx.x >> 6;
    float acc = 0.f;
    for (int n = st + chunk; n < en; n += 4) acc += h[(size_t)n * 64 + col];
    __shared__ float s[256];
    __shared__ float mean[64];
    s[threadIdx.x] = acc;
    __syncthreads();
    if (chunk == 0) {
        float tot = s[col] + s[64 + col] + s[128 + col] + s[192 + col];
        int c = en - st;
        mean[col] = tot / (float)(c > 1 ? c : 1);
    }
    __syncthreads();
    if (threadIdx.x < 10) {
        int j = threadIdx.x;
        float o = cbias[j];
#pragma unroll
        for (int k = 0; k < 64; k++) o += mean[k] * cw[k * 10 + j];
        out[g * 10 + j] = o;
    }
}

extern "C" void kernel_launch(void* const* d_in, const int* in_sizes, int n_in,
                              void* d_out, int out_size, void* d_ws, size_t ws_size,
                              hipStream_t stream) {
    const int* x      = (const int*)d_in[0];
    const int* ei     = (const int*)d_in[1];
    const int* et     = (const int*)d_in[2];
    const int* batch  = (const int*)d_in[3];
    const float* se   = (const float*)d_in[4];
    const float* ce   = (const float*)d_in[5];
    const float* pw   = (const float*)d_in[6];
    const float* pb   = (const float*)d_in[7];
    const float* w1   = (const float*)d_in[8];
    const float* root1= (const float*)d_in[9];
    const float* b1   = (const float*)d_in[10];
    const float* w2   = (const float*)d_in[11];
    const float* root2= (const float*)d_in[12];
    const float* b2   = (const float*)d_in[13];
    const float* cw   = (const float*)d_in[14];
    const float* cbias= (const float*)d_in[15];
    float* out = (float*)d_out;

    char* ws = (char*)d_ws;
    __bf16* aggb = (__bf16*)(ws + AGG_OFF);
    int*   hist  = (int*)(ws + HIST_OFF);
    int*   esrc  = (int*)(ws + ESRC_OFF);
    __bf16* h1b  = (__bf16*)(ws + H1_OFF);
    float* h2    = (float*)(ws + H2_OFF);
    __bf16* wt2h = (__bf16*)(ws + WT2H_OFF);
    __bf16* wt2l = (__bf16*)(ws + WT2L_OFF);
    float* tw    = (float*)(ws + TW_OFF);
    unsigned char* cbarr = (unsigned char*)(ws + CB_OFF);

    // zero the histogram only (1.2MB)
    (void)hipMemsetAsync(hist, 0, (size_t)NSEG * 4, stream);

    // single fused LDS-free dispatch: W2-split | tW build | cb bytes | rank+place
    int rank_blocks = RB_BASE + (NE + 255) / 256;
    k_rank_prep<<<rank_blocks, 256, 0, stream>>>(ei, et, hist, esrc,
                                                 x, se, ce, pw, pb,
                                                 root1, w1, b1, root2, w2,
                                                 wt2h, wt2l, tw, cbarr);

    // layer 1 (fully fused via weighted tables)
    k_l1<<<(NN * 8 + 255) / 256, 256, 0, stream>>>(hist, esrc, cbarr, tw, h1b);

    // layer 2
    k_gather64<<<(NSEG * 8 + 255) / 256, 256, 0, stream>>>(hist, esrc, h1b, aggb);
    k_combine_l2<<<(NN + 63) / 64, 256, 0, stream>>>(h1b, aggb, wt2h, wt2l, b2, h2);

    // fused pooling + classifier
    k_pool_final<<<NG, 256, 0, stream>>>(h2, batch, cw, cbias, out);
}

// Round 22
// 180.346 us; speedup vs baseline: 1.0609x; 1.0536x over previous
//
#include <hip/hip_runtime.h>

#define NN 100000
#define NE 1200000
#define NG 512
#define NSEG (3 * NN)
#define BCAP 32                   // per-(rel,dst) bucket capacity (lambda=4, P(deg>=32)~4e-13)

typedef __bf16 bf16x8 __attribute__((ext_vector_type(8)));
typedef float f32x4 __attribute__((ext_vector_type(4)));

// ---- workspace layout (bytes), all 16B-aligned ----
static constexpr size_t AGG_OFF   = 0;                                  // NSEG*64 bf16 (layer-2 agg)
static constexpr size_t AGG_BYTES = (size_t)NSEG * 64 * 2;              // 38.4MB
static constexpr size_t HIST_OFF  = AGG_OFF + AGG_BYTES;                // NSEG ints
static constexpr size_t ESRC_OFF  = HIST_OFF + (size_t)NSEG * 4;        // NSEG*BCAP ints (38.4MB)
static constexpr size_t H1_OFF    = ESRC_OFF + (size_t)NSEG * BCAP * 4; // NN*64 bf16
static constexpr size_t H2_OFF    = H1_OFF + (size_t)NN * 64 * 2;       // NN*64 bf16
static constexpr size_t WT2H_OFF  = H2_OFF + (size_t)NN * 64 * 2;       // 64*256 bf16
static constexpr size_t WT2L_OFF  = WT2H_OFF + 64 * 256 * 2;
static constexpr size_t TW_OFF    = WT2L_OFF + 64 * 256 * 2;            // 4*256*64 f32 (tRoot,tW1[0..2])
static constexpr size_t CB_OFF    = TW_OFF + 4 * 256 * 64 * 4;          // NN bytes

// async global->LDS, 16B per lane
__device__ __forceinline__ void async_copy16(void* lds, const void* g) {
    __builtin_amdgcn_global_load_lds(
        (const __attribute__((address_space(1))) void*)g,
        (__attribute__((address_space(3))) void*)lds, 16, 0, 0);
}

__device__ __forceinline__ void prepw_elem(const float* root, const float* w,
                                           __bf16* wh, __bf16* wl, int cin, int t) {
    int kt = 4 * cin;
    if (t >= 64 * kt) return;
    int j = t / kt, k = t % kt;
    int sidx = k / cin, kk = k % cin;
    float v = (sidx == 0) ? root[kk * 64 + j]
                          : w[((size_t)(sidx - 1) * cin + kk) * 64 + j];
    __bf16 h = (__bf16)v;
    wh[t] = h;
    wl[t] = (__bf16)(v - (float)h);
}

// compute one combo row (32 outputs) of the pre-MLP from LDS sW/sB
__device__ __forceinline__ void combo_row(int cmb, const float* se, const float* ce,
                                          const float* sW, const float* sB, float* outr) {
    int s = cmb >> 4, c = cmb & 15;
    float in[16];
#pragma unroll
    for (int k = 0; k < 8; k++) in[k] = se[s * 8 + k];
#pragma unroll
    for (int k = 0; k < 8; k++) in[8 + k] = ce[c * 8 + k];
    float acc[32];
#pragma unroll
    for (int j = 0; j < 32; j++) acc[j] = sB[j];
#pragma unroll
    for (int k = 0; k < 16; k++) {
        float hv = in[k];
#pragma unroll
        for (int j = 0; j < 32; j++) acc[j] += hv * sW[k * 32 + j];
    }
#pragma unroll
    for (int j = 0; j < 32; j++) outr[j] = fmaxf(acc[j], 0.f);
}

// ---- fused: prep (blocks 0..470) + rank-and-place (blocks 471..)
//   blocks 0..63   : split W2|root2 into bf16 hi/lo
//   blocks 64..79  : build tW tables (only 64 combo rows per block -> 10.6KB LDS,
//                    so rank blocks keep ~7 blocks/CU instead of R19's 4)
//   blocks 80..470 : cb[n] combo bytes
//   blocks 471..   : hist atomic -> rank; place payload directly in bucket
#define RB_BASE 471
__global__ __launch_bounds__(256)
void k_rank_prep(const int* __restrict__ ei, const int* __restrict__ et,
                 int* __restrict__ hist, int* __restrict__ esrc,
                 const int* __restrict__ x, const float* __restrict__ se,
                 const float* __restrict__ ce, const float* __restrict__ pw,
                 const float* __restrict__ pb,
                 const float* __restrict__ root1, const float* __restrict__ w1,
                 const float* __restrict__ b1,
                 const float* __restrict__ root2, const float* __restrict__ w2,
                 __bf16* __restrict__ wh2, __bf16* __restrict__ wl2,
                 float* __restrict__ tw, unsigned char* __restrict__ cb) {
    int b = blockIdx.x, t = threadIdx.x;
    if (b >= RB_BASE) {
        int e = (b - RB_BASE) * 256 + t;
        if (e >= NE) return;
        int s = ei[e];
        int d = ei[NE + e];
        int r = et[e];
        int2 xv = *(const int2*)(x + 2 * s);       // independent 8B load, fills shadow
        int seg = r * NN + d;
        int rank = atomicAdd(&hist[seg], 1);
        if (rank < BCAP)
            esrc[(size_t)seg * BCAP + rank] = s | ((xv.x * 16 + xv.y) << 17);
        return;
    }
    if (b < 64) {
        prepw_elem(root2, w2, wh2, wl2, 64, b * 256 + t);
    } else if (b < 80) {
        // build tW tables; only the 64 combo rows this block consumes
        __shared__ float sW[16 * 32];
        __shared__ float sB[32];
        __shared__ float sTab[64 * 33];
        for (int i = t; i < 512; i += 256) sW[i] = pw[i];
        if (t < 32) sB[t] = pb[t];
        __syncthreads();
        int rbase = ((b - 64) & 3) * 64;
        if (t < 64) {
            float row[32];
            combo_row(rbase + t, se, ce, sW, sB, row);
#pragma unroll
            for (int j = 0; j < 32; j++) sTab[t * 33 + j] = row[j];
        }
        __syncthreads();
        int ti = (b - 64) >> 2;               // 0..3: tRoot, tW1[0..2]
        int rloc = t >> 2;                    // 0..63
        int row = rbase + rloc;
        int c0 = (t & 3) * 16;
        const float* Wsrc = (ti == 0) ? root1 : (w1 + (size_t)(ti - 1) * 32 * 64);
        float acc[16];
#pragma unroll
        for (int j = 0; j < 16; j++) acc[j] = (ti == 0) ? b1[c0 + j] : 0.f;
        for (int k = 0; k < 32; k++) {
            float hv = sTab[rloc * 33 + k];
#pragma unroll
            for (int j = 0; j < 16; j++) acc[j] += hv * Wsrc[k * 64 + c0 + j];
        }
        float* o = tw + (size_t)ti * 256 * 64 + (size_t)row * 64 + c0;
#pragma unroll
        for (int j = 0; j < 16; j += 4)
            *(float4*)(o + j) = make_float4(acc[j], acc[j + 1], acc[j + 2], acc[j + 3]);
    } else {
        int n = (b - 80) * 256 + t;
        if (n < NN) cb[n] = (unsigned char)(x[2 * n] * 16 + x[2 * n + 1]);
    }
}

// ---- layer 1 (fused): h1[n] = relu(tRoot[cb[n]] + sum_r mean_r(tW1r[cmb(src)]))
__global__ __launch_bounds__(256)
void k_l1(const int* __restrict__ hist, const int* __restrict__ esrc,
          const unsigned char* __restrict__ cb,
          const float* __restrict__ tw, __bf16* __restrict__ h1b) {
    int tid = blockIdx.x * 256 + threadIdx.x;
    int n = tid >> 3;
    int p = tid & 7;
    if (n >= NN) return;
    const float* tr = tw + (size_t)cb[n] * 64 + p * 8;
    float4 a0 = *(const float4*)tr;
    float4 a1 = *(const float4*)(tr + 4);
#pragma unroll
    for (int r = 0; r < 3; r++) {
        const float* tb = tw + (size_t)(r + 1) * 256 * 64 + p * 8;
        int seg = r * NN + n;
        int cnt = hist[seg];
        int m = cnt < BCAP ? cnt : BCAP;
        const int* eb = esrc + (size_t)seg * BCAP;
        float4 r0 = make_float4(0.f, 0.f, 0.f, 0.f);
        float4 r1 = make_float4(0.f, 0.f, 0.f, 0.f);
        for (int i = 0; i < m; i++) {
            int cmb = (eb[i] >> 17) & 0xFF;
            const float* row = tb + (size_t)cmb * 64;
            float4 v0 = *(const float4*)row;
            float4 v1 = *(const float4*)(row + 4);
            r0.x += v0.x; r0.y += v0.y; r0.z += v0.z; r0.w += v0.w;
            r1.x += v1.x; r1.y += v1.y; r1.z += v1.z; r1.w += v1.w;
        }
        float inv = 1.f / (float)(cnt > 1 ? cnt : 1);
        a0.x += r0.x * inv; a0.y += r0.y * inv; a0.z += r0.z * inv; a0.w += r0.w * inv;
        a1.x += r1.x * inv; a1.y += r1.y * inv; a1.z += r1.z * inv; a1.w += r1.w * inv;
    }
    bf16x8 o;
    o[0] = (__bf16)fmaxf(a0.x, 0.f); o[1] = (__bf16)fmaxf(a0.y, 0.f);
    o[2] = (__bf16)fmaxf(a0.z, 0.f); o[3] = (__bf16)fmaxf(a0.w, 0.f);
    o[4] = (__bf16)fmaxf(a1.x, 0.f); o[5] = (__bf16)fmaxf(a1.y, 0.f);
    o[6] = (__bf16)fmaxf(a1.z, 0.f); o[7] = (__bf16)fmaxf(a1.w, 0.f);
    *(bf16x8*)(h1b + (size_t)n * 64 + p * 8) = o;
}

// ---- layer-2 gather: bf16 rows (128B/edge) from buckets; bf16 agg
__global__ __launch_bounds__(256)
void k_gather64(const int* __restrict__ hist, const int* __restrict__ esrc,
                const __bf16* __restrict__ h, __bf16* __restrict__ agg) {
    int tid = blockIdx.x * 256 + threadIdx.x;
    int seg = tid >> 3;
    int p = tid & 7;
    if (seg >= NSEG) return;
    int cnt = hist[seg];
    int m = cnt < BCAP ? cnt : BCAP;
    const int* eb = esrc + (size_t)seg * BCAP;
    float acc[8];
#pragma unroll
    for (int j = 0; j < 8; j++) acc[j] = 0.f;
    int i = 0;
    for (; i + 4 <= m; i += 4) {
        int s0 = eb[i] & 0x1FFFF, s1 = eb[i + 1] & 0x1FFFF;
        int s2 = eb[i + 2] & 0x1FFFF, s3 = eb[i + 3] & 0x1FFFF;
        bf16x8 v0 = *(const bf16x8*)(h + (size_t)s0 * 64 + p * 8);
        bf16x8 v1 = *(const bf16x8*)(h + (size_t)s1 * 64 + p * 8);
        bf16x8 v2 = *(const bf16x8*)(h + (size_t)s2 * 64 + p * 8);
        bf16x8 v3 = *(const bf16x8*)(h + (size_t)s3 * 64 + p * 8);
#pragma unroll
        for (int j = 0; j < 8; j++)
            acc[j] += ((float)v0[j] + (float)v1[j]) + ((float)v2[j] + (float)v3[j]);
    }
    for (; i < m; i++) {
        int s = eb[i] & 0x1FFFF;
        bf16x8 v = *(const bf16x8*)(h + (size_t)s * 64 + p * 8);
#pragma unroll
        for (int j = 0; j < 8; j++) acc[j] += (float)v[j];
    }
    float inv = 1.f / (float)(cnt > 1 ? cnt : 1);
    bf16x8 o;
#pragma unroll
    for (int j = 0; j < 8; j++) o[j] = (__bf16)(acc[j] * inv);
    *(bf16x8*)(agg + (size_t)seg * 64 + p * 8) = o;
}

// ---- layer-2 combine (bf16 A, split-bf16 weights; bf16 out)
__global__ __launch_bounds__(256, 1)
void k_combine_l2(const __bf16* __restrict__ h1b, const __bf16* __restrict__ aggb,
                  const __bf16* __restrict__ wh, const __bf16* __restrict__ wl,
                  const float* __restrict__ bias, __bf16* __restrict__ h_out) {
    constexpr int KT = 256;
    __shared__ __bf16 sINb[64 * 64];
    __shared__ __bf16 sWH[64 * 64];
    __shared__ __bf16 sWL[64 * 64];

    const int tid = threadIdx.x;
    const int wave = tid >> 6;
    const int lane = tid & 63;
    const int cA = lane & 15;
    const int kg = lane >> 4;
    const int n0 = blockIdx.x * 64;

    f32x4 acc[4];
#pragma unroll
    for (int nb = 0; nb < 4; nb++) {
        float bv = bias[nb * 16 + cA];
        acc[nb][0] = bv; acc[nb][1] = bv; acc[nb][2] = bv; acc[nb][3] = bv;
    }

    for (int c = 0; c < 4; c++) {
        if (c) __syncthreads();
#pragma unroll
        for (int i = 0; i < 2; i++) {
            int F = tid + i * 256;
            int row = F >> 3, j = F & 7;
            int jor = j ^ (row & 7);
            int n = n0 + row; if (n > NN - 1) n = NN - 1;
            const __bf16* src = (c == 0)
                ? h1b + (size_t)n * 64 + jor * 8
                : aggb + ((size_t)(c - 1) * NN + n) * 64 + jor * 8;
            async_copy16(sINb + (size_t)F * 8, src);
        }
#pragma unroll
        for (int i = 0; i < 2; i++) {
            int F = tid + i * 256;
            int col = F >> 3, s = F & 7;
            int sor = s ^ (col & 7);
            async_copy16(sWH + (size_t)F * 8, wh + (size_t)col * KT + c * 64 + sor * 8);
            async_copy16(sWL + (size_t)F * 8, wl + (size_t)col * KT + c * 64 + sor * 8);
        }
        __syncthreads();
#pragma unroll
        for (int ks = 0; ks < 2; ks++) {
            const int rowL = wave * 16 + cA;
            const int s8 = ks * 4 + kg;
            bf16x8 ah = ((const bf16x8*)sINb)[rowL * 8 + (s8 ^ (rowL & 7))];
#pragma unroll
            for (int nb = 0; nb < 4; nb++) {
                const int col = nb * 16 + cA;
                const int bs = col * 8 + (s8 ^ (col & 7));
                bf16x8 bh = ((const bf16x8*)sWH)[bs];
                bf16x8 bl = ((const bf16x8*)sWL)[bs];
                acc[nb] = __builtin_amdgcn_mfma_f32_16x16x32_bf16(ah, bh, acc[nb], 0, 0, 0);
                acc[nb] = __builtin_amdgcn_mfma_f32_16x16x32_bf16(ah, bl, acc[nb], 0, 0, 0);
            }
        }
    }
#pragma unroll
    for (int nb = 0; nb < 4; nb++) {
#pragma unroll
        for (int r = 0; r < 4; r++) {
            int n = n0 + wave * 16 + kg * 4 + r;
            if (n < NN)
                h_out[(size_t)n * 64 + nb * 16 + cA] = (__bf16)fmaxf(acc[nb][r], 0.f);
        }
    }
}

// ---- fused mean-pool + classifier: block g -> out[g][0..9] (bf16 h2 input)
__global__ __launch_bounds__(256)
void k_pool_final(const __bf16* __restrict__ h, const int* __restrict__ batch,
                  const float* __restrict__ cw, const float* __restrict__ cbias,
                  float* __restrict__ out) {
    int g = blockIdx.x;
    auto lb = [&](int v) {
        int lo = 0, hi = NN;
        while (lo < hi) {
            int m = (lo + hi) >> 1;
            if (batch[m] < v) lo = m + 1; else hi = m;
        }
        return lo;
    };
    int st = lb(g), en = lb(g + 1);
    int col = threadIdx.x & 63, chunk = threadIdx.x >> 6;
    float acc = 0.f;
    for (int n = st + chunk; n < en; n += 4) acc += (float)h[(size_t)n * 64 + col];
    __shared__ float s[256];
    __shared__ float mean[64];
    s[threadIdx.x] = acc;
    __syncthreads();
    if (chunk == 0) {
        float tot = s[col] + s[64 + col] + s[128 + col] + s[192 + col];
        int c = en - st;
        mean[col] = tot / (float)(c > 1 ? c : 1);
    }
    __syncthreads();
    if (threadIdx.x < 10) {
        int j = threadIdx.x;
        float o = cbias[j];
#pragma unroll
        for (int k = 0; k < 64; k++) o += mean[k] * cw[k * 10 + j];
        out[g * 10 + j] = o;
    }
}

extern "C" void kernel_launch(void* const* d_in, const int* in_sizes, int n_in,
                              void* d_out, int out_size, void* d_ws, size_t ws_size,
                              hipStream_t stream) {
    const int* x      = (const int*)d_in[0];
    const int* ei     = (const int*)d_in[1];
    const int* et     = (const int*)d_in[2];
    const int* batch  = (const int*)d_in[3];
    const float* se   = (const float*)d_in[4];
    const float* ce   = (const float*)d_in[5];
    const float* pw   = (const float*)d_in[6];
    const float* pb   = (const float*)d_in[7];
    const float* w1   = (const float*)d_in[8];
    const float* root1= (const float*)d_in[9];
    const float* b1   = (const float*)d_in[10];
    const float* w2   = (const float*)d_in[11];
    const float* root2= (const float*)d_in[12];
    const float* b2   = (const float*)d_in[13];
    const float* cw   = (const float*)d_in[14];
    const float* cbias= (const float*)d_in[15];
    float* out = (float*)d_out;

    char* ws = (char*)d_ws;
    __bf16* aggb = (__bf16*)(ws + AGG_OFF);
    int*   hist  = (int*)(ws + HIST_OFF);
    int*   esrc  = (int*)(ws + ESRC_OFF);
    __bf16* h1b  = (__bf16*)(ws + H1_OFF);
    __bf16* h2b  = (__bf16*)(ws + H2_OFF);
    __bf16* wt2h = (__bf16*)(ws + WT2H_OFF);
    __bf16* wt2l = (__bf16*)(ws + WT2L_OFF);
    float* tw    = (float*)(ws + TW_OFF);
    unsigned char* cbarr = (unsigned char*)(ws + CB_OFF);

    // zero the histogram only (1.2MB)
    (void)hipMemsetAsync(hist, 0, (size_t)NSEG * 4, stream);

    // fused prep + rank-and-place (single dispatch; table build now 10.6KB LDS)
    int rank_blocks = RB_BASE + (NE + 255) / 256;
    k_rank_prep<<<rank_blocks, 256, 0, stream>>>(ei, et, hist, esrc,
                                                 x, se, ce, pw, pb,
                                                 root1, w1, b1, root2, w2,
                                                 wt2h, wt2l, tw, cbarr);

    // layer 1 (fully fused via weighted tables)
    k_l1<<<(NN * 8 + 255) / 256, 256, 0, stream>>>(hist, esrc, cbarr, tw, h1b);

    // layer 2
    k_gather64<<<(NSEG * 8 + 255) / 256, 256, 0, stream>>>(hist, esrc, h1b, aggb);
    k_combine_l2<<<(NN + 63) / 64, 256, 0, stream>>>(h1b, aggb, wt2h, wt2l, b2, h2b);

    // fused pooling + classifier
    k_pool_final<<<NG, 256, 0, stream>>>(h2b, batch, cw, cbias, out);
}